// Round 17
// baseline (205.907 us; speedup 1.0000x reference)
//
#include <hip/hip_runtime.h>

#define B_ 4
#define N_ 2048
#define D_ 512
#define H_ 8
#define DH_ 64
#define ROWS_ 8192
#define KSCALE 0.18033688011112042f   // (1/8) * log2(e)

typedef float f32x4 __attribute__((ext_vector_type(4)));
typedef short short8v __attribute__((ext_vector_type(8)));
typedef short short4v __attribute__((ext_vector_type(4)));
typedef unsigned uint4v __attribute__((ext_vector_type(4)));

#define WAITVM(N) asm volatile("s_waitcnt vmcnt(" #N ")" ::: "memory")

__device__ __forceinline__ short f2bf(float f) {
    unsigned u = __builtin_bit_cast(unsigned, f);
    u += 0x7FFFu + ((u >> 16) & 1u);   // round-to-nearest-even
    return (short)(u >> 16);
}

__device__ __forceinline__ unsigned cvtpk_bf16(float lo, float hi) {
    unsigned r;
    asm("v_cvt_pk_bf16_f32 %0, %1, %2" : "=v"(r) : "v"(lo), "v"(hi));
    return r;
}

// async global->LDS, 16B per lane; lds dest = wave-uniform base + lane*16.
__device__ __forceinline__ void gload16(const void* g, void* l) {
    __builtin_amdgcn_global_load_lds(
        (const __attribute__((address_space(1))) unsigned int*)g,
        (__attribute__((address_space(3))) unsigned int*)l, 16, 0, 0);
}

__device__ __forceinline__ void waitvm0_barrier() {
    asm volatile("s_waitcnt vmcnt(0)" ::: "memory");
    __builtin_amdgcn_s_barrier();
}

// ---------------------------------------------------------------------------
// LayerNorm fp32-in -> bf16-out. One wave per row of 512; 4 rows/block.
// ---------------------------------------------------------------------------
__global__ __launch_bounds__(256) void ln_bf16_kernel(const float* __restrict__ x,
                                                      const float* __restrict__ g,
                                                      const float* __restrict__ bb,
                                                      short* __restrict__ out) {
    int wave = threadIdx.x >> 6;
    int lane = threadIdx.x & 63;
    int row  = blockIdx.x * 4 + wave;
    const float* xr = x + (size_t)row * D_;

    float4 v0 = ((const float4*)xr)[lane * 2 + 0];
    float4 v1 = ((const float4*)xr)[lane * 2 + 1];

    float s = v0.x + v0.y + v0.z + v0.w + v1.x + v1.y + v1.z + v1.w;
    #pragma unroll
    for (int off = 32; off; off >>= 1) s += __shfl_xor(s, off, 64);
    float mu = s * (1.0f / D_);

    float d0 = v0.x - mu, d1 = v0.y - mu, d2 = v0.z - mu, d3 = v0.w - mu;
    float d4 = v1.x - mu, d5 = v1.y - mu, d6 = v1.z - mu, d7 = v1.w - mu;
    float vs = d0*d0 + d1*d1 + d2*d2 + d3*d3 + d4*d4 + d5*d5 + d6*d6 + d7*d7;
    #pragma unroll
    for (int off = 32; off; off >>= 1) vs += __shfl_xor(vs, off, 64);
    float rstd = rsqrtf(vs * (1.0f / D_) + 1e-5f);

    float4 g0 = ((const float4*)g)[lane * 2 + 0];
    float4 g1 = ((const float4*)g)[lane * 2 + 1];
    float4 b0 = ((const float4*)bb)[lane * 2 + 0];
    float4 b1 = ((const float4*)bb)[lane * 2 + 1];

    short8v ov;
    ov[0] = f2bf(d0 * rstd * g0.x + b0.x);
    ov[1] = f2bf(d1 * rstd * g0.y + b0.y);
    ov[2] = f2bf(d2 * rstd * g0.z + b0.z);
    ov[3] = f2bf(d3 * rstd * g0.w + b0.w);
    ov[4] = f2bf(d4 * rstd * g1.x + b1.x);
    ov[5] = f2bf(d5 * rstd * g1.y + b1.y);
    ov[6] = f2bf(d6 * rstd * g1.z + b1.z);
    ov[7] = f2bf(d7 * rstd * g1.w + b1.w);
    *(short8v*)&out[(size_t)row * D_ + lane * 8] = ov;
}

// ---------------------------------------------------------------------------
// Weight transpose + cvt: W[K][N] fp32 -> WT[N][K] bf16. 64x64 tile per block.
// ---------------------------------------------------------------------------
__global__ __launch_bounds__(256) void wt_kernel(const float* __restrict__ W,
                                                 short* __restrict__ WT,
                                                 int K, int N) {
    __shared__ short Ts[64][72];
    int tid = threadIdx.x;
    int n0 = blockIdx.x * 64, k0 = blockIdx.y * 64;

    #pragma unroll
    for (int i = 0; i < 4; ++i) {
        int idx = tid + i * 256;            // 1024 float4 chunks
        int k = idx >> 4, nq = (idx & 15) * 4;
        float4 wv = *(const float4*)&W[(size_t)(k0 + k) * N + n0 + nq];
        short4v t;
        t[0] = f2bf(wv.x); t[1] = f2bf(wv.y); t[2] = f2bf(wv.z); t[3] = f2bf(wv.w);
        *(short4v*)&Ts[k][nq] = t;
    }
    __syncthreads();

    int n = tid >> 2, kq = (tid & 3) * 16;
    short8v o0, o1;
    #pragma unroll
    for (int j = 0; j < 8; ++j) { o0[j] = Ts[kq + j][n]; o1[j] = Ts[kq + 8 + j][n]; }
    *(short8v*)&WT[(size_t)(n0 + n) * K + k0 + kq]     = o0;
    *(short8v*)&WT[(size_t)(n0 + n) * K + k0 + kq + 8] = o1;
}

// ---------------------------------------------------------------------------
// bf16 MFMA GEMM: 128x64 tile, BK=64. RING-3 global_load_lds buffers with
// COUNTED vmcnt(6): stage(t+2) issued before compute(t); the wait only
// requires tile t+1 landed, t+2 stays in flight across the barrier ->
// prefetch distance 2 (~2 compute phases to cover first-touch latency).
// Both-sides XOR swizzle; hoisted pointers; blockIdx.x = ROW panel (T1).
// QKVMODE: Q-columns (col<512) pre-scaled by KSCALE (softmax fold);
//          V-columns (col>=1024) written TRANSPOSED per head into vtg.
// ---------------------------------------------------------------------------
template<bool GELU, bool RESID, bool OUTBF, bool QKVMODE>
__global__ __launch_bounds__(256) void gemm_bf16(const short* __restrict__ A,
                                                 const short* __restrict__ BT,
                                                 const float* __restrict__ bias,
                                                 const float* __restrict__ resid,
                                                 float* __restrict__ Cf,
                                                 short* __restrict__ Cb,
                                                 short* __restrict__ vtg,
                                                 int M, int N, int K) {
    __shared__ short As[3][8192];   // [buf][128*64]
    __shared__ short Bs[3][4096];   // [buf][64*64]
    int tid = threadIdx.x;
    int l = tid & 63, w = tid >> 6;
    int wr = w >> 1, wc = w & 1;
    int l15 = l & 15, lg = l >> 4;
    int row0 = blockIdx.x * 128, col0 = blockIdx.y * 64;   // x = row panel (T1)

    int rsub = l >> 3;
    int kq_  = ((l & 7) ^ rsub) * 8;         // source pre-swizzle
    int rsw  = l15 & 7;                      // read-side swizzle

    const short* ap[4];
    const short* bp[2];
    #pragma unroll
    for (int i = 0; i < 4; ++i)
        ap[i] = A + (size_t)(row0 + i * 32 + w * 8 + rsub) * K + kq_;
    bp[0] = BT + (size_t)(col0 + w * 8 + rsub) * K + kq_;
    bp[1] = BT + (size_t)(col0 + 32 + w * 8 + rsub) * K + kq_;

    int aoff0 = (wr * 64 + l15) * 64 + ((lg ^ rsw)) * 8;
    int aoff1 = (wr * 64 + l15) * 64 + (((4 + lg) ^ rsw)) * 8;
    int boff0 = (wc * 32 + l15) * 64 + ((lg ^ rsw)) * 8;
    int boff1 = (wc * 32 + l15) * 64 + (((4 + lg) ^ rsw)) * 8;

    const f32x4 zero4 = {0.f, 0.f, 0.f, 0.f};
    f32x4 acc[4][2];
    #pragma unroll
    for (int m = 0; m < 4; ++m)
        #pragma unroll
        for (int n = 0; n < 2; ++n) acc[m][n] = zero4;

    auto stage = [&](int bf) {
        #pragma unroll
        for (int i = 0; i < 4; ++i) {
            gload16(ap[i], &As[bf][(i * 4 + w) * 512]);
            ap[i] += 64;
        }
        gload16(bp[0], &Bs[bf][w * 512]);       bp[0] += 64;
        gload16(bp[1], &Bs[bf][(4 + w) * 512]); bp[1] += 64;
    };

    auto compute = [&](int bf) {
        const short* Ab = As[bf];
        const short* Bb = Bs[bf];
        #pragma unroll
        for (int ks = 0; ks < 2; ++ks) {
            short8v a[4], bfr[2];
            #pragma unroll
            for (int m = 0; m < 4; ++m)
                a[m] = *(const short8v*)&Ab[(ks ? aoff1 : aoff0) + m * 1024];
            #pragma unroll
            for (int n = 0; n < 2; ++n)
                bfr[n] = *(const short8v*)&Bb[(ks ? boff1 : boff0) + n * 1024];
            __builtin_amdgcn_s_setprio(1);
            #pragma unroll
            for (int m = 0; m < 4; ++m)
                #pragma unroll
                for (int n = 0; n < 2; ++n)
                    acc[m][n] = __builtin_amdgcn_mfma_f32_16x16x32_bf16(a[m], bfr[n], acc[m][n], 0, 0, 0);
            __builtin_amdgcn_s_setprio(0);
        }
    };

    int NT = K >> 6;
    stage(0);
    stage(1);
    WAITVM(6);                    // tile 0 landed; tile 1 in flight
    __builtin_amdgcn_s_barrier();

    int cb = 0, sb = 2;
    for (int t = 0; t < NT; ++t) {
        if (t + 2 < NT) {
            stage(sb);
            compute(cb);
            WAITVM(6);            // tile t+1 landed; t+2 in flight
        } else {
            compute(cb);
            WAITVM(0);            // tail: drain
        }
        __builtin_amdgcn_s_barrier();
        cb = (cb == 2) ? 0 : cb + 1;
        sb = (sb == 2) ? 0 : sb + 1;
    }

    if (QKVMODE && col0 >= 1024) {
        // V block: write transposed into vtg[b*512 + hd][n], 4-bf16 packs
        int b = row0 >> 11;
        int nb = row0 & 2047;
        #pragma unroll
        for (int n = 0; n < 2; ++n) {
            int col = col0 + wc * 32 + n * 16 + l15;
            float bv = bias[col];
            int hd = col - 1024;
            size_t vrow = (size_t)(b * 512 + hd) * N_;
            #pragma unroll
            for (int m = 0; m < 4; ++m) {
                int nbase = nb + wr * 64 + m * 16 + lg * 4;
                uint2 uu;
                uu.x = cvtpk_bf16(acc[m][n][0] + bv, acc[m][n][1] + bv);
                uu.y = cvtpk_bf16(acc[m][n][2] + bv, acc[m][n][3] + bv);
                *(uint2*)&vtg[vrow + nbase] = uu;
            }
        }
        return;
    }

    float qscl = (QKVMODE && col0 < 512) ? KSCALE : 1.0f;
    #pragma unroll
    for (int n = 0; n < 2; ++n) {
        int col = col0 + wc * 32 + n * 16 + l15;
        float bv = bias[col];
        #pragma unroll
        for (int m = 0; m < 4; ++m) {
            #pragma unroll
            for (int i = 0; i < 4; ++i) {
                int row = row0 + wr * 64 + m * 16 + lg * 4 + i;
                size_t off = (size_t)row * N + col;
                float v = acc[m][n][i] + bv;
                if (RESID) v += resid[off];
                if (GELU)  v = 0.5f * v * (1.0f + erff(v * 0.70710678118654752f));
                if (QKVMODE) v *= qscl;
                if (OUTBF) Cb[off] = f2bf(v);
                else       Cf[off] = v;
            }
        }
    }
}

// ---------------------------------------------------------------------------
// Flash attention, max-free softmax, 32 q-rows per wave (2 q-frags).
// Block = 128 q-rows of one (b,h); 4 waves; grid (bh, qt) bh-major (T1).
// Swapped+key-permuted QK^T; P in registers; ones-MFMA row-sum.
// (identical to the 177.7us build)
// ---------------------------------------------------------------------------
__global__ __launch_bounds__(256) void fattn_bf16(const short* __restrict__ qkvb,
                                                  const short* __restrict__ vtg,
                                                  short* __restrict__ attnout) {
    __shared__ short Ks[2][4096];
    __shared__ short Vt[2][4096];

    int tid = threadIdx.x;
    int l = tid & 63, w = tid >> 6;          // 4 waves
    int l15 = l & 15, lg = l >> 4;
    int bh = blockIdx.x, qt = blockIdx.y;    // bh-major: same-head -> same XCD
    int b = bh >> 3, h = bh & 7;
    int n0 = qt * 128;
    int qb = w * 32;

    int hK = ((l15 >> 2) << 1) | (l15 & 1);
    int hV = l15 & 7;
    int kperm = ((l15 >> 2) << 3) + (l15 & 3);

    int koff0 = kperm * 64 + (lg ^ hK) * 8;
    int koff1 = kperm * 64 + (((4 + lg) ^ hK)) * 8;
    int voff0 = l15 * 64 + (lg ^ hV) * 8;
    int voff1 = l15 * 64 + (((4 + lg) ^ hV)) * 8;

    // Q b-fragments in registers (whole kernel; pre-scaled by KSCALE)
    short8v bQ[2][2];
    #pragma unroll
    for (int qi = 0; qi < 2; ++qi)
        #pragma unroll
        for (int ks = 0; ks < 2; ++ks)
            bQ[qi][ks] = *(const short8v*)
                &qkvb[(size_t)(b * N_ + n0 + qb + qi * 16 + l15) * 1536 + h * 64 + ks * 32 + lg * 8];

    short8v ones;
    #pragma unroll
    for (int j = 0; j < 8; ++j) ones[j] = (short)0x3F80;   // bf16 1.0

    const f32x4 zero4 = {0.f, 0.f, 0.f, 0.f};
    f32x4 o[2][4], l_acc[2];
    #pragma unroll
    for (int qi = 0; qi < 2; ++qi) {
        l_acc[qi] = zero4;
        #pragma unroll
        for (int df = 0; df < 4; ++df) o[qi][df] = zero4;
    }

    // staging: wave w, i in {0,1} -> 8 rows (w*2+i)*8 + (l>>3), slot l&7
    int lr = l >> 3, lc = l & 7;
    const short* kp[2];
    const short* vp[2];
    #pragma unroll
    for (int i = 0; i < 2; ++i) {
        int g = w * 2 + i, r = g * 8 + lr;
        int hKs = ((g & 3) << 1) | (lr & 1);
        kp[i] = &qkvb[(size_t)(b * N_ + r) * 1536 + 512 + h * 64 + ((lc ^ hKs) << 3)];
        vp[i] = &vtg[((size_t)bh * 64 + r) * N_ + ((lc ^ lr) << 3)];
    }

    auto stage = [&](int bf) {
        #pragma unroll
        for (int i = 0; i < 2; ++i) {
            int g = w * 2 + i;
            gload16(kp[i], &Ks[bf][g * 512]); kp[i] += 64 * 1536;
            gload16(vp[i], &Vt[bf][g * 512]); vp[i] += 64;
        }
    };

    auto compute = [&](int bf) {
        // ---- QK^T (swapped, key-permuted); s is already log2-domain
        f32x4 s[2][4];
        #pragma unroll
        for (int kf = 0; kf < 4; ++kf) {
            short8v aK0 = *(const short8v*)&Ks[bf][koff0 + (kf >> 1) * 2048 + (kf & 1) * 256];
            short8v aK1 = *(const short8v*)&Ks[bf][koff1 + (kf >> 1) * 2048 + (kf & 1) * 256];
            __builtin_amdgcn_s_setprio(1);
            #pragma unroll
            for (int qi = 0; qi < 2; ++qi) {
                s[qi][kf] = __builtin_amdgcn_mfma_f32_16x16x32_bf16(aK0, bQ[qi][0], zero4, 0, 0, 0);
                s[qi][kf] = __builtin_amdgcn_mfma_f32_16x16x32_bf16(aK1, bQ[qi][1], s[qi][kf], 0, 0, 0);
            }
            __builtin_amdgcn_s_setprio(0);
        }

        // ---- max-free softmax: P = exp2(S'), pack straight to PV B-frags
        short8v bP[2][2];
        #pragma unroll
        for (int qi = 0; qi < 2; ++qi) {
            #pragma unroll
            for (int kf = 0; kf < 4; ++kf)
                #pragma unroll
                for (int i = 0; i < 4; ++i)
                    s[qi][kf][i] = exp2f(s[qi][kf][i]);
            #pragma unroll
            for (int ks = 0; ks < 2; ++ks) {
                uint4v u;
                u[0] = cvtpk_bf16(s[qi][2 * ks][0],     s[qi][2 * ks][1]);
                u[1] = cvtpk_bf16(s[qi][2 * ks][2],     s[qi][2 * ks][3]);
                u[2] = cvtpk_bf16(s[qi][2 * ks + 1][0], s[qi][2 * ks + 1][1]);
                u[3] = cvtpk_bf16(s[qi][2 * ks + 1][2], s[qi][2 * ks + 1][3]);
                bP[qi][ks] = __builtin_bit_cast(short8v, u);
            }
        }

        // ---- row-sum via ones-MFMA; PV (swapped), V reads shared across qi
        __builtin_amdgcn_s_setprio(1);
        #pragma unroll
        for (int qi = 0; qi < 2; ++qi) {
            l_acc[qi] = __builtin_amdgcn_mfma_f32_16x16x32_bf16(ones, bP[qi][0], l_acc[qi], 0, 0, 0);
            l_acc[qi] = __builtin_amdgcn_mfma_f32_16x16x32_bf16(ones, bP[qi][1], l_acc[qi], 0, 0, 0);
        }
        __builtin_amdgcn_s_setprio(0);
        #pragma unroll
        for (int df = 0; df < 4; ++df) {
            short8v aV0 = *(const short8v*)&Vt[bf][voff0 + df * 1024];
            short8v aV1 = *(const short8v*)&Vt[bf][voff1 + df * 1024];
            __builtin_amdgcn_s_setprio(1);
            #pragma unroll
            for (int qi = 0; qi < 2; ++qi) {
                o[qi][df] = __builtin_amdgcn_mfma_f32_16x16x32_bf16(aV0, bP[qi][0], o[qi][df], 0, 0, 0);
                o[qi][df] = __builtin_amdgcn_mfma_f32_16x16x32_bf16(aV1, bP[qi][1], o[qi][df], 0, 0, 0);
            }
            __builtin_amdgcn_s_setprio(0);
        }
    };

    stage(0);
    waitvm0_barrier();

    for (int t2 = 0; t2 < 16; ++t2) {
        stage(1);
        compute(0);
        waitvm0_barrier();
        if (t2 + 1 < 16) stage(0);
        compute(1);
        waitvm0_barrier();
    }

    // epilogue: normalize and store
    #pragma unroll
    for (int qi = 0; qi < 2; ++qi) {
        float linv = 1.0f / l_acc[qi][0];
        size_t rowb = (size_t)(b * N_ + n0 + qb + qi * 16 + l15) * D_ + h * 64;
        #pragma unroll
        for (int df = 0; df < 4; ++df) {
            uint2 uu;
            uu.x = cvtpk_bf16(o[qi][df][0] * linv, o[qi][df][1] * linv);
            uu.y = cvtpk_bf16(o[qi][df][2] * linv, o[qi][df][3] * linv);
            *(uint2*)&attnout[rowb + df * 16 + lg * 4] = uu;
        }
    }
}

// ---------------------------------------------------------------------------
extern "C" void kernel_launch(void* const* d_in, const int* in_sizes, int n_in,
                              void* d_out, int out_size, void* d_ws, size_t ws_size,
                              hipStream_t stream) {
    const float* x      = (const float*)d_in[0];
    const float* ln1_g  = (const float*)d_in[1];
    const float* ln1_b  = (const float*)d_in[2];
    const float* Wqkv   = (const float*)d_in[3];
    const float* bqkv   = (const float*)d_in[4];
    const float* Wproj  = (const float*)d_in[5];
    const float* bproj  = (const float*)d_in[6];
    const float* ln2_g  = (const float*)d_in[7];
    const float* ln2_b  = (const float*)d_in[8];
    const float* W1     = (const float*)d_in[9];
    const float* b1     = (const float*)d_in[10];
    const float* W2     = (const float*)d_in[11];
    const float* b2     = (const float*)d_in[12];
    float* out = (float*)d_out;

    char* ws = (char*)d_ws;
    short* h_bf    = (short*)(ws + (size_t)0);
    short* qkv_bf  = (short*)(ws + ((size_t)8  << 20));
    short* vtg     = (short*)(ws + ((size_t)32 << 20));
    short* attn_bf = (short*)(ws + ((size_t)40 << 20));
    float* x2      = (float*)(ws + ((size_t)48 << 20));
    short* h2_bf   = (short*)(ws + ((size_t)64 << 20));
    short* ffh_bf  = (short*)(ws + ((size_t)72 << 20));
    short* WTqkv   = (short*)(ws + ((size_t)104 << 20));
    short* WTproj  = (short*)(ws + ((size_t)106 << 20));
    short* WT1     = (short*)(ws + ((size_t)108 << 20));
    short* WT2     = (short*)(ws + ((size_t)110 << 20));

    dim3 blk(256);

    // weight transposes (bf16)
    wt_kernel<<<dim3(24, 8),  blk, 0, stream>>>(Wqkv,  WTqkv,  512,  1536);
    wt_kernel<<<dim3(8, 8),   blk, 0, stream>>>(Wproj, WTproj, 512,  512);
    wt_kernel<<<dim3(32, 8),  blk, 0, stream>>>(W1,    WT1,    512,  2048);
    wt_kernel<<<dim3(8, 32),  blk, 0, stream>>>(W2,    WT2,    2048, 512);

    // 1. h = LN1(x)  (bf16)
    ln_bf16_kernel<<<ROWS_ / 4, blk, 0, stream>>>(x, ln1_g, ln1_b, h_bf);

    // 2. qkv = h @ Wqkv + bqkv  (bf16): Q pre-scaled, V written to vtg
    gemm_bf16<false, false, true, true><<<dim3(64, 24), blk, 0, stream>>>(
        h_bf, WTqkv, bqkv, nullptr, nullptr, qkv_bf, vtg, ROWS_, 1536, 512);

    // 3. attention (bf16 out): 128 q-rows/block, bh-major grid
    fattn_bf16<<<dim3(32, 16), blk, 0, stream>>>(qkv_bf, vtg, attn_bf);

    // 4. x2 = x + attn @ Wproj + bproj  (fp32 out)
    gemm_bf16<false, true, false, false><<<dim3(64, 8), blk, 0, stream>>>(
        attn_bf, WTproj, bproj, x, x2, nullptr, nullptr, ROWS_, 512, 512);

    // 5. h2 = LN2(x2)  (bf16)
    ln_bf16_kernel<<<ROWS_ / 4, blk, 0, stream>>>(x2, ln2_g, ln2_b, h2_bf);

    // 6. ffh = gelu(h2 @ W1 + b1)  (bf16 out)
    gemm_bf16<true, false, true, false><<<dim3(64, 32), blk, 0, stream>>>(
        h2_bf, WT1, b1, nullptr, nullptr, ffh_bf, nullptr, ROWS_, 2048, 512);

    // 7. out = x2 + ffh @ W2 + b2  (fp32 out)
    gemm_bf16<false, true, false, false><<<dim3(64, 8), blk, 0, stream>>>(
        ffh_bf, WT2, b2, x2, out, nullptr, nullptr, ROWS_, 512, 2048);
}

// Round 18
// 169.793 us; speedup vs baseline: 1.2127x; 1.2127x over previous
//
#include <hip/hip_runtime.h>

#define B_ 4
#define N_ 2048
#define D_ 512
#define H_ 8
#define DH_ 64
#define ROWS_ 8192
#define KSCALE 0.18033688011112042f   // (1/8) * log2(e)

typedef float f32x4 __attribute__((ext_vector_type(4)));
typedef short short8v __attribute__((ext_vector_type(8)));
typedef short short4v __attribute__((ext_vector_type(4)));
typedef unsigned uint4v __attribute__((ext_vector_type(4)));

__device__ __forceinline__ short f2bf(float f) {
    unsigned u = __builtin_bit_cast(unsigned, f);
    u += 0x7FFFu + ((u >> 16) & 1u);   // round-to-nearest-even
    return (short)(u >> 16);
}

__device__ __forceinline__ unsigned cvtpk_bf16(float lo, float hi) {
    unsigned r;
    asm("v_cvt_pk_bf16_f32 %0, %1, %2" : "=v"(r) : "v"(lo), "v"(hi));
    return r;
}

// async global->LDS, 16B per lane; lds dest = wave-uniform base + lane*16.
__device__ __forceinline__ void gload16(const void* g, void* l) {
    __builtin_amdgcn_global_load_lds(
        (const __attribute__((address_space(1))) unsigned int*)g,
        (__attribute__((address_space(3))) unsigned int*)l, 16, 0, 0);
}

__device__ __forceinline__ void waitvm0_barrier() {
    asm volatile("s_waitcnt vmcnt(0)" ::: "memory");
    __builtin_amdgcn_s_barrier();
}

// ---------------------------------------------------------------------------
// LayerNorm fp32-in -> bf16-out. One wave per row of 512; 4 rows/block.
// ---------------------------------------------------------------------------
__global__ __launch_bounds__(256) void ln_bf16_kernel(const float* __restrict__ x,
                                                      const float* __restrict__ g,
                                                      const float* __restrict__ bb,
                                                      short* __restrict__ out) {
    int wave = threadIdx.x >> 6;
    int lane = threadIdx.x & 63;
    int row  = blockIdx.x * 4 + wave;
    const float* xr = x + (size_t)row * D_;

    float4 v0 = ((const float4*)xr)[lane * 2 + 0];
    float4 v1 = ((const float4*)xr)[lane * 2 + 1];

    float s = v0.x + v0.y + v0.z + v0.w + v1.x + v1.y + v1.z + v1.w;
    #pragma unroll
    for (int off = 32; off; off >>= 1) s += __shfl_xor(s, off, 64);
    float mu = s * (1.0f / D_);

    float d0 = v0.x - mu, d1 = v0.y - mu, d2 = v0.z - mu, d3 = v0.w - mu;
    float d4 = v1.x - mu, d5 = v1.y - mu, d6 = v1.z - mu, d7 = v1.w - mu;
    float vs = d0*d0 + d1*d1 + d2*d2 + d3*d3 + d4*d4 + d5*d5 + d6*d6 + d7*d7;
    #pragma unroll
    for (int off = 32; off; off >>= 1) vs += __shfl_xor(vs, off, 64);
    float rstd = rsqrtf(vs * (1.0f / D_) + 1e-5f);

    float4 g0 = ((const float4*)g)[lane * 2 + 0];
    float4 g1 = ((const float4*)g)[lane * 2 + 1];
    float4 b0 = ((const float4*)bb)[lane * 2 + 0];
    float4 b1 = ((const float4*)bb)[lane * 2 + 1];

    short8v ov;
    ov[0] = f2bf(d0 * rstd * g0.x + b0.x);
    ov[1] = f2bf(d1 * rstd * g0.y + b0.y);
    ov[2] = f2bf(d2 * rstd * g0.z + b0.z);
    ov[3] = f2bf(d3 * rstd * g0.w + b0.w);
    ov[4] = f2bf(d4 * rstd * g1.x + b1.x);
    ov[5] = f2bf(d5 * rstd * g1.y + b1.y);
    ov[6] = f2bf(d6 * rstd * g1.z + b1.z);
    ov[7] = f2bf(d7 * rstd * g1.w + b1.w);
    *(short8v*)&out[(size_t)row * D_ + lane * 8] = ov;
}

// ---------------------------------------------------------------------------
// Fused weight transpose + cvt for ALL FOUR weights in one launch.
// W[K][N] fp32 -> WT[N][K] bf16, 64x64 tile per block; block picks its
// (W, WT, K, N, tile) from a uniform table keyed on blockIdx.x ranges.
// ---------------------------------------------------------------------------
__global__ __launch_bounds__(256) void wt4_kernel(const float* __restrict__ Wqkv,
                                                  const float* __restrict__ Wproj,
                                                  const float* __restrict__ W1,
                                                  const float* __restrict__ W2,
                                                  short* __restrict__ WTqkv,
                                                  short* __restrict__ WTproj,
                                                  short* __restrict__ WT1,
                                                  short* __restrict__ WT2) {
    __shared__ short Ts[64][72];
    int tid = threadIdx.x;
    int idx = blockIdx.x;

    const float* W;
    short* WT;
    int K, N, nt, rel;
    if (idx < 192)      { W = Wqkv;  WT = WTqkv;  K = 512;  N = 1536; nt = 24; rel = idx; }
    else if (idx < 256) { W = Wproj; WT = WTproj; K = 512;  N = 512;  nt = 8;  rel = idx - 192; }
    else if (idx < 512) { W = W1;    WT = WT1;    K = 512;  N = 2048; nt = 32; rel = idx - 256; }
    else                { W = W2;    WT = WT2;    K = 2048; N = 512;  nt = 8;  rel = idx - 512; }
    int n0 = (rel % nt) * 64, k0 = (rel / nt) * 64;

    #pragma unroll
    for (int i = 0; i < 4; ++i) {
        int t = tid + i * 256;              // 1024 float4 chunks
        int k = t >> 4, nq = (t & 15) * 4;
        float4 wv = *(const float4*)&W[(size_t)(k0 + k) * N + n0 + nq];
        short4v tv;
        tv[0] = f2bf(wv.x); tv[1] = f2bf(wv.y); tv[2] = f2bf(wv.z); tv[3] = f2bf(wv.w);
        *(short4v*)&Ts[k][nq] = tv;
    }
    __syncthreads();

    int n = tid >> 2, kq = (tid & 3) * 16;
    short8v o0, o1;
    #pragma unroll
    for (int j = 0; j < 8; ++j) { o0[j] = Ts[kq + j][n]; o1[j] = Ts[kq + 8 + j][n]; }
    *(short8v*)&WT[(size_t)(n0 + n) * K + k0 + kq]     = o0;
    *(short8v*)&WT[(size_t)(n0 + n) * K + k0 + kq + 8] = o1;
}

// ---------------------------------------------------------------------------
// bf16 MFMA GEMM (best measured config): 128x64 tile, BK=64,
// double-buffered global_load_lds, unrolled-by-2 (literal buffer indices),
// hoisted pointers, both-sides XOR swizzle. blockIdx.x = ROW panel (T1).
// QKVMODE: Q-columns (col<512) pre-scaled by KSCALE (softmax fold);
//          V-columns (col>=1024) written TRANSPOSED per head into vtg.
// ---------------------------------------------------------------------------
template<bool GELU, bool RESID, bool OUTBF, bool QKVMODE>
__global__ __launch_bounds__(256) void gemm_bf16(const short* __restrict__ A,
                                                 const short* __restrict__ BT,
                                                 const float* __restrict__ bias,
                                                 const float* __restrict__ resid,
                                                 float* __restrict__ Cf,
                                                 short* __restrict__ Cb,
                                                 short* __restrict__ vtg,
                                                 int M, int N, int K) {
    __shared__ short As[2][8192];   // [bf][128*64]
    __shared__ short Bs[2][4096];   // [bf][64*64]
    int tid = threadIdx.x;
    int l = tid & 63, w = tid >> 6;
    int wr = w >> 1, wc = w & 1;
    int l15 = l & 15, lg = l >> 4;
    int row0 = blockIdx.x * 128, col0 = blockIdx.y * 64;   // x = row panel (T1)

    int rsub = l >> 3;
    int kq_  = ((l & 7) ^ rsub) * 8;
    int rsw  = l15 & 7;              // read-side swizzle (row&7)

    const short* ap[4];
    const short* bp[2];
    #pragma unroll
    for (int i = 0; i < 4; ++i)
        ap[i] = A + (size_t)(row0 + i * 32 + w * 8 + rsub) * K + kq_;
    bp[0] = BT + (size_t)(col0 + w * 8 + rsub) * K + kq_;
    bp[1] = BT + (size_t)(col0 + 32 + w * 8 + rsub) * K + kq_;

    int aoff0 = (wr * 64 + l15) * 64 + ((lg ^ rsw)) * 8;
    int aoff1 = (wr * 64 + l15) * 64 + (((4 + lg) ^ rsw)) * 8;
    int boff0 = (wc * 32 + l15) * 64 + ((lg ^ rsw)) * 8;
    int boff1 = (wc * 32 + l15) * 64 + (((4 + lg) ^ rsw)) * 8;

    const f32x4 zero4 = {0.f, 0.f, 0.f, 0.f};
    f32x4 acc[4][2];
    #pragma unroll
    for (int m = 0; m < 4; ++m)
        #pragma unroll
        for (int n = 0; n < 2; ++n) acc[m][n] = zero4;

    auto stage = [&](int bf) {
        #pragma unroll
        for (int i = 0; i < 4; ++i) {
            gload16(ap[i], &As[bf][(i * 4 + w) * 512]);
            ap[i] += 64;
        }
        gload16(bp[0], &Bs[bf][w * 512]);       bp[0] += 64;
        gload16(bp[1], &Bs[bf][(4 + w) * 512]); bp[1] += 64;
    };

    auto compute = [&](int bf) {
        #pragma unroll
        for (int ks = 0; ks < 2; ++ks) {
            short8v a[4], bfr[2];
            #pragma unroll
            for (int m = 0; m < 4; ++m)
                a[m] = *(const short8v*)&As[bf][(ks ? aoff1 : aoff0) + m * 1024];
            #pragma unroll
            for (int n = 0; n < 2; ++n)
                bfr[n] = *(const short8v*)&Bs[bf][(ks ? boff1 : boff0) + n * 1024];
            __builtin_amdgcn_s_setprio(1);
            #pragma unroll
            for (int m = 0; m < 4; ++m)
                #pragma unroll
                for (int n = 0; n < 2; ++n)
                    acc[m][n] = __builtin_amdgcn_mfma_f32_16x16x32_bf16(a[m], bfr[n], acc[m][n], 0, 0, 0);
            __builtin_amdgcn_s_setprio(0);
        }
    };

    stage(0);
    waitvm0_barrier();

    int NH = K >> 7;                 // NT/2
    for (int t2 = 0; t2 < NH; ++t2) {
        stage(1);
        compute(0);
        waitvm0_barrier();
        if (t2 + 1 < NH) stage(0);
        compute(1);
        waitvm0_barrier();
    }

    if (QKVMODE && col0 >= 1024) {
        // V block: write transposed into vtg[b*512 + hd][n], 4-bf16 packs
        int b = row0 >> 11;
        int nb = row0 & 2047;
        #pragma unroll
        for (int n = 0; n < 2; ++n) {
            int col = col0 + wc * 32 + n * 16 + l15;
            float bv = bias[col];
            int hd = col - 1024;
            size_t vrow = (size_t)(b * 512 + hd) * N_;
            #pragma unroll
            for (int m = 0; m < 4; ++m) {
                int nbase = nb + wr * 64 + m * 16 + lg * 4;
                uint2 uu;
                uu.x = cvtpk_bf16(acc[m][n][0] + bv, acc[m][n][1] + bv);
                uu.y = cvtpk_bf16(acc[m][n][2] + bv, acc[m][n][3] + bv);
                *(uint2*)&vtg[vrow + nbase] = uu;
            }
        }
        return;
    }

    float qscl = (QKVMODE && col0 < 512) ? KSCALE : 1.0f;
    #pragma unroll
    for (int n = 0; n < 2; ++n) {
        int col = col0 + wc * 32 + n * 16 + l15;
        float bv = bias[col];
        #pragma unroll
        for (int m = 0; m < 4; ++m) {
            #pragma unroll
            for (int i = 0; i < 4; ++i) {
                int row = row0 + wr * 64 + m * 16 + lg * 4 + i;
                size_t off = (size_t)row * N + col;
                float v = acc[m][n][i] + bv;
                if (RESID) v += resid[off];
                if (GELU)  v = 0.5f * v * (1.0f + erff(v * 0.70710678118654752f));
                if (QKVMODE) v *= qscl;
                if (OUTBF) Cb[off] = f2bf(v);
                else       Cf[off] = v;
            }
        }
    }
}

// ---------------------------------------------------------------------------
// Flash attention, max-free softmax, 32 q-rows per wave (2 q-frags).
// Block = 128 q-rows of one (b,h); 4 waves; grid (bh, qt) bh-major (T1).
// Swapped+key-permuted QK^T; P in registers; ones-MFMA row-sum.
// (the 177.7us build, unchanged)
// ---------------------------------------------------------------------------
__global__ __launch_bounds__(256) void fattn_bf16(const short* __restrict__ qkvb,
                                                  const short* __restrict__ vtg,
                                                  short* __restrict__ attnout) {
    __shared__ short Ks[2][4096];
    __shared__ short Vt[2][4096];

    int tid = threadIdx.x;
    int l = tid & 63, w = tid >> 6;          // 4 waves
    int l15 = l & 15, lg = l >> 4;
    int bh = blockIdx.x, qt = blockIdx.y;    // bh-major: same-head -> same XCD
    int b = bh >> 3, h = bh & 7;
    int n0 = qt * 128;
    int qb = w * 32;

    int hK = ((l15 >> 2) << 1) | (l15 & 1);
    int hV = l15 & 7;
    int kperm = ((l15 >> 2) << 3) + (l15 & 3);

    int koff0 = kperm * 64 + (lg ^ hK) * 8;
    int koff1 = kperm * 64 + (((4 + lg) ^ hK)) * 8;
    int voff0 = l15 * 64 + (lg ^ hV) * 8;
    int voff1 = l15 * 64 + (((4 + lg) ^ hV)) * 8;

    // Q b-fragments in registers (whole kernel; pre-scaled by KSCALE)
    short8v bQ[2][2];
    #pragma unroll
    for (int qi = 0; qi < 2; ++qi)
        #pragma unroll
        for (int ks = 0; ks < 2; ++ks)
            bQ[qi][ks] = *(const short8v*)
                &qkvb[(size_t)(b * N_ + n0 + qb + qi * 16 + l15) * 1536 + h * 64 + ks * 32 + lg * 8];

    short8v ones;
    #pragma unroll
    for (int j = 0; j < 8; ++j) ones[j] = (short)0x3F80;   // bf16 1.0

    const f32x4 zero4 = {0.f, 0.f, 0.f, 0.f};
    f32x4 o[2][4], l_acc[2];
    #pragma unroll
    for (int qi = 0; qi < 2; ++qi) {
        l_acc[qi] = zero4;
        #pragma unroll
        for (int df = 0; df < 4; ++df) o[qi][df] = zero4;
    }

    // staging: wave w, i in {0,1} -> 8 rows (w*2+i)*8 + (l>>3), slot l&7
    int lr = l >> 3, lc = l & 7;
    const short* kp[2];
    const short* vp[2];
    #pragma unroll
    for (int i = 0; i < 2; ++i) {
        int g = w * 2 + i, r = g * 8 + lr;
        int hKs = ((g & 3) << 1) | (lr & 1);
        kp[i] = &qkvb[(size_t)(b * N_ + r) * 1536 + 512 + h * 64 + ((lc ^ hKs) << 3)];
        vp[i] = &vtg[((size_t)bh * 64 + r) * N_ + ((lc ^ lr) << 3)];
    }

    auto stage = [&](int bf) {
        #pragma unroll
        for (int i = 0; i < 2; ++i) {
            int g = w * 2 + i;
            gload16(kp[i], &Ks[bf][g * 512]); kp[i] += 64 * 1536;
            gload16(vp[i], &Vt[bf][g * 512]); vp[i] += 64;
        }
    };

    auto compute = [&](int bf) {
        // ---- QK^T (swapped, key-permuted); s is already log2-domain
        f32x4 s[2][4];
        #pragma unroll
        for (int kf = 0; kf < 4; ++kf) {
            short8v aK0 = *(const short8v*)&Ks[bf][koff0 + (kf >> 1) * 2048 + (kf & 1) * 256];
            short8v aK1 = *(const short8v*)&Ks[bf][koff1 + (kf >> 1) * 2048 + (kf & 1) * 256];
            __builtin_amdgcn_s_setprio(1);
            #pragma unroll
            for (int qi = 0; qi < 2; ++qi) {
                s[qi][kf] = __builtin_amdgcn_mfma_f32_16x16x32_bf16(aK0, bQ[qi][0], zero4, 0, 0, 0);
                s[qi][kf] = __builtin_amdgcn_mfma_f32_16x16x32_bf16(aK1, bQ[qi][1], s[qi][kf], 0, 0, 0);
            }
            __builtin_amdgcn_s_setprio(0);
        }

        // ---- max-free softmax: P = exp2(S'), pack straight to PV B-frags
        short8v bP[2][2];
        #pragma unroll
        for (int qi = 0; qi < 2; ++qi) {
            #pragma unroll
            for (int kf = 0; kf < 4; ++kf)
                #pragma unroll
                for (int i = 0; i < 4; ++i)
                    s[qi][kf][i] = exp2f(s[qi][kf][i]);
            #pragma unroll
            for (int ks = 0; ks < 2; ++ks) {
                uint4v u;
                u[0] = cvtpk_bf16(s[qi][2 * ks][0],     s[qi][2 * ks][1]);
                u[1] = cvtpk_bf16(s[qi][2 * ks][2],     s[qi][2 * ks][3]);
                u[2] = cvtpk_bf16(s[qi][2 * ks + 1][0], s[qi][2 * ks + 1][1]);
                u[3] = cvtpk_bf16(s[qi][2 * ks + 1][2], s[qi][2 * ks + 1][3]);
                bP[qi][ks] = __builtin_bit_cast(short8v, u);
            }
        }

        // ---- row-sum via ones-MFMA; PV (swapped), V reads shared across qi
        __builtin_amdgcn_s_setprio(1);
        #pragma unroll
        for (int qi = 0; qi < 2; ++qi) {
            l_acc[qi] = __builtin_amdgcn_mfma_f32_16x16x32_bf16(ones, bP[qi][0], l_acc[qi], 0, 0, 0);
            l_acc[qi] = __builtin_amdgcn_mfma_f32_16x16x32_bf16(ones, bP[qi][1], l_acc[qi], 0, 0, 0);
        }
        __builtin_amdgcn_s_setprio(0);
        #pragma unroll
        for (int df = 0; df < 4; ++df) {
            short8v aV0 = *(const short8v*)&Vt[bf][voff0 + df * 1024];
            short8v aV1 = *(const short8v*)&Vt[bf][voff1 + df * 1024];
            __builtin_amdgcn_s_setprio(1);
            #pragma unroll
            for (int qi = 0; qi < 2; ++qi) {
                o[qi][df] = __builtin_amdgcn_mfma_f32_16x16x32_bf16(aV0, bP[qi][0], o[qi][df], 0, 0, 0);
                o[qi][df] = __builtin_amdgcn_mfma_f32_16x16x32_bf16(aV1, bP[qi][1], o[qi][df], 0, 0, 0);
            }
            __builtin_amdgcn_s_setprio(0);
        }
    };

    stage(0);
    waitvm0_barrier();

    for (int t2 = 0; t2 < 16; ++t2) {
        stage(1);
        compute(0);
        waitvm0_barrier();
        if (t2 + 1 < 16) stage(0);
        compute(1);
        waitvm0_barrier();
    }

    // epilogue: normalize and store
    #pragma unroll
    for (int qi = 0; qi < 2; ++qi) {
        float linv = 1.0f / l_acc[qi][0];
        size_t rowb = (size_t)(b * N_ + n0 + qb + qi * 16 + l15) * D_ + h * 64;
        #pragma unroll
        for (int df = 0; df < 4; ++df) {
            uint2 uu;
            uu.x = cvtpk_bf16(o[qi][df][0] * linv, o[qi][df][1] * linv);
            uu.y = cvtpk_bf16(o[qi][df][2] * linv, o[qi][df][3] * linv);
            *(uint2*)&attnout[rowb + df * 16 + lg * 4] = uu;
        }
    }
}

// ---------------------------------------------------------------------------
extern "C" void kernel_launch(void* const* d_in, const int* in_sizes, int n_in,
                              void* d_out, int out_size, void* d_ws, size_t ws_size,
                              hipStream_t stream) {
    const float* x      = (const float*)d_in[0];
    const float* ln1_g  = (const float*)d_in[1];
    const float* ln1_b  = (const float*)d_in[2];
    const float* Wqkv   = (const float*)d_in[3];
    const float* bqkv   = (const float*)d_in[4];
    const float* Wproj  = (const float*)d_in[5];
    const float* bproj  = (const float*)d_in[6];
    const float* ln2_g  = (const float*)d_in[7];
    const float* ln2_b  = (const float*)d_in[8];
    const float* W1     = (const float*)d_in[9];
    const float* b1     = (const float*)d_in[10];
    const float* W2     = (const float*)d_in[11];
    const float* b2     = (const float*)d_in[12];
    float* out = (float*)d_out;

    char* ws = (char*)d_ws;
    short* h_bf    = (short*)(ws + (size_t)0);
    short* qkv_bf  = (short*)(ws + ((size_t)8  << 20));
    short* vtg     = (short*)(ws + ((size_t)32 << 20));
    short* attn_bf = (short*)(ws + ((size_t)40 << 20));
    float* x2      = (float*)(ws + ((size_t)48 << 20));
    short* h2_bf   = (short*)(ws + ((size_t)64 << 20));
    short* ffh_bf  = (short*)(ws + ((size_t)72 << 20));
    short* WTqkv   = (short*)(ws + ((size_t)104 << 20));
    short* WTproj  = (short*)(ws + ((size_t)106 << 20));
    short* WT1     = (short*)(ws + ((size_t)108 << 20));
    short* WT2     = (short*)(ws + ((size_t)110 << 20));

    dim3 blk(256);

    // weight transposes (bf16), all four in ONE launch
    wt4_kernel<<<768, blk, 0, stream>>>(Wqkv, Wproj, W1, W2,
                                        WTqkv, WTproj, WT1, WT2);

    // 1. h = LN1(x)  (bf16)
    ln_bf16_kernel<<<ROWS_ / 4, blk, 0, stream>>>(x, ln1_g, ln1_b, h_bf);

    // 2. qkv = h @ Wqkv + bqkv  (bf16): Q pre-scaled, V written to vtg
    gemm_bf16<false, false, true, true><<<dim3(64, 24), blk, 0, stream>>>(
        h_bf, WTqkv, bqkv, nullptr, nullptr, qkv_bf, vtg, ROWS_, 1536, 512);

    // 3. attention (bf16 out): 128 q-rows/block, bh-major grid
    fattn_bf16<<<dim3(32, 16), blk, 0, stream>>>(qkv_bf, vtg, attn_bf);

    // 4. x2 = x + attn @ Wproj + bproj  (fp32 out)
    gemm_bf16<false, true, false, false><<<dim3(64, 8), blk, 0, stream>>>(
        attn_bf, WTproj, bproj, x, x2, nullptr, nullptr, ROWS_, 512, 512);

    // 5. h2 = LN2(x2)  (bf16)
    ln_bf16_kernel<<<ROWS_ / 4, blk, 0, stream>>>(x2, ln2_g, ln2_b, h2_bf);

    // 6. ffh = gelu(h2 @ W1 + b1)  (bf16 out)
    gemm_bf16<true, false, true, false><<<dim3(64, 32), blk, 0, stream>>>(
        h2_bf, WT1, b1, nullptr, nullptr, ffh_bf, nullptr, ROWS_, 2048, 512);

    // 7. out = x2 + ffh @ W2 + b2  (fp32 out)
    gemm_bf16<false, true, false, false><<<dim3(64, 8), blk, 0, stream>>>(
        ffh_bf, WT2, b2, x2, out, nullptr, nullptr, ROWS_, 512, 2048);
}